// Round 10
// baseline (121.656 us; speedup 1.0000x reference)
//
#include <hip/hip_runtime.h>
#include <hip/hip_bf16.h>
#include <math.h>

// B=4, T=128, S=512, D=512. Outputs: attn_h (4,128,512) then align (4,128,512), fp32.
// 4-kernel pipeline:
//   K1 fused_front (640): Ew=exp(2(inp@Wq^T+bq)) bf16, Eu=exp(2 ctx@Wc^T) bf16,
//      GT[b]=(WL@ctx_b^T) bf16, Y0=inp@WR^T+bout fp32
//   K2 align (1024): Sraw[b,t,s] = V - 2*sum_d v[d]/(1+Ew*Eu)  (== sum v*tanh)
//      8t x 8s per wave, paired-k bf16 loads (64 MB total traffic vs 192 fp32)
//   K3 softmax (512): alignv (fp32, d_out) + P_bf (bf16, ws)
//   K4 gemm_att (64): attn = P_bf @ GT^T + Y0   (MFMA, K=512)

typedef __attribute__((ext_vector_type(8))) short short8;
typedef __attribute__((ext_vector_type(4))) float f32x4;
typedef unsigned short ushort_t;

static __device__ __forceinline__ unsigned short f2bf(float x) {
    union { __hip_bfloat16 h; unsigned short u; } c;
    c.h = __float2bfloat16(x);
    return c.u;
}
static __device__ __forceinline__ int bf2x(float lo, float hi) {
    return (int)(((unsigned)f2bf(hi) << 16) | (unsigned)f2bf(lo));
}
static __device__ __forceinline__ float bfu_lo(unsigned u) {
    union { unsigned u; float f; } c; c.u = u << 16; return c.f;
}
static __device__ __forceinline__ float bfu_hi(unsigned u) {
    union { unsigned u; float f; } c; c.u = u & 0xffff0000u; return c.f;
}

template<bool BF>
static __device__ __forceinline__ void load16(const void* base, size_t elemoff,
                                              int4& r0, int4& r1) {
    if (BF) {
        const int4* p = (const int4*)((const ushort_t*)base + elemoff);
        r0 = p[0]; r1 = p[1];
    } else {
        const float4* p = (const float4*)((const float*)base + elemoff);
        float4 a = p[0], b = p[1], c = p[2], d = p[3];
        r0.x = bf2x(a.x, a.y); r0.y = bf2x(a.z, a.w);
        r0.z = bf2x(b.x, b.y); r0.w = bf2x(b.z, b.w);
        r1.x = bf2x(c.x, c.y); r1.y = bf2x(c.z, c.w);
        r1.z = bf2x(d.x, d.y); r1.w = bf2x(d.z, d.w);
    }
}

// ---------------------------------------------------------------------------
// MFMA NT GEMM tile: C[m,n] = sum_k A[m,k]*W[n,k] (+bias). 64x64 tile, BK=64,
// 256 thr = 4 waves (2x2 of 32x32), 2x2 MFMA 16x16x32 per 32-K step.
// LDS rows padded to 72 bf16 (<=2-way bank aliasing on b128 = free).
// EPI: 0 fp32+bias; 1 fp32 exp(2*(x+bias)); 2 bf16; 3 fp32+partial;
//      4 bf16 exp(2*(x+bias)).
// ---------------------------------------------------------------------------
template<bool A_BF, bool W_BF, int EPI>
static __device__ __forceinline__ void gemm_body(
    ushort_t* As, ushort_t* Ws,
    const void* A, const void* W, const float* bias, const float* partial,
    void* Cv, int K, int lda, int ldw, int ldc, int bm, int bn)
{
    const int tid = threadIdx.x;
    const int wave = tid >> 6, lane = tid & 63;
    const int mh = (wave & 1) * 32, nh = (wave >> 1) * 32;
    const int quad = lane >> 4, l16 = lane & 15;
    const int srow = tid >> 2, schunk = tid & 3;

    const size_t aoff = (size_t)(bm + srow) * lda + schunk * 16;
    const size_t woff = (size_t)(bn + srow) * ldw + schunk * 16;
    int4* AsW = (int4*)&As[srow * 72 + schunk * 16];
    int4* WsW = (int4*)&Ws[srow * 72 + schunk * 16];

    f32x4 acc00 = {0.f, 0.f, 0.f, 0.f}, acc01 = acc00, acc10 = acc00, acc11 = acc00;

    int4 a0r, a1r, w0r, w1r;
    load16<A_BF>(A, aoff, a0r, a1r);
    load16<W_BF>(W, woff, w0r, w1r);

    for (int k0 = 0; k0 < K; k0 += 64) {
        AsW[0] = a0r; AsW[1] = a1r;
        WsW[0] = w0r; WsW[1] = w1r;
        __syncthreads();
        if (k0 + 64 < K) {
            load16<A_BF>(A, aoff + k0 + 64, a0r, a1r);
            load16<W_BF>(W, woff + k0 + 64, w0r, w1r);
        }
        #pragma unroll
        for (int kk = 0; kk < 64; kk += 32) {
            short8 a0 = *(const short8*)&As[(mh + l16) * 72 + kk + quad * 8];
            short8 a1 = *(const short8*)&As[(mh + 16 + l16) * 72 + kk + quad * 8];
            short8 b0 = *(const short8*)&Ws[(nh + l16) * 72 + kk + quad * 8];
            short8 b1 = *(const short8*)&Ws[(nh + 16 + l16) * 72 + kk + quad * 8];
            acc00 = __builtin_amdgcn_mfma_f32_16x16x32_bf16(a0, b0, acc00, 0, 0, 0);
            acc01 = __builtin_amdgcn_mfma_f32_16x16x32_bf16(a0, b1, acc01, 0, 0, 0);
            acc10 = __builtin_amdgcn_mfma_f32_16x16x32_bf16(a1, b0, acc10, 0, 0, 0);
            acc11 = __builtin_amdgcn_mfma_f32_16x16x32_bf16(a1, b1, acc11, 0, 0, 0);
        }
        __syncthreads();
    }

    const int col0 = bn + nh + l16;
    const int col1 = col0 + 16;
    float bias0 = bias ? bias[col0] : 0.f;
    float bias1 = bias ? bias[col1] : 0.f;

    f32x4 accs[2][2] = {{acc00, acc01}, {acc10, acc11}};
    #pragma unroll
    for (int mt = 0; mt < 2; ++mt) {
        #pragma unroll
        for (int r = 0; r < 4; ++r) {
            int row = bm + mh + mt * 16 + quad * 4 + r;
            size_t rowoff = (size_t)row * ldc;
            float v0 = accs[mt][0][r] + bias0;
            float v1 = accs[mt][1][r] + bias1;
            if (EPI == 1 || EPI == 4) { v0 = __expf(2.f * v0); v1 = __expf(2.f * v1); }
            if (EPI == 3) { v0 += partial[rowoff + col0]; v1 += partial[rowoff + col1]; }
            if (EPI == 2 || EPI == 4) {
                ushort_t* C = (ushort_t*)Cv;
                C[rowoff + col0] = f2bf(v0);
                C[rowoff + col1] = f2bf(v1);
            } else {
                float* C = (float*)Cv;
                C[rowoff + col0] = v0;
                C[rowoff + col1] = v1;
            }
        }
    }
}

// ---------------------------------------------------------------------------
// K1: fused front (640 GEMM blocks)
// [0,64)    Ew = exp(2*(inp@Wq^T + bq))   -> bf16
// [64,320)  Eu = exp(2*(ctx@Wc^T))        -> bf16
// [320,576) GT[b][n,s] = sum_d WL[n,d]*ctx[b][s,d]  -> bf16
// [576,640) Y0 = inp@WR^T + bout          -> fp32
// ---------------------------------------------------------------------------
__global__ __launch_bounds__(256) void fused_front(
    const float* __restrict__ inp, const float* __restrict__ ctx,
    const float* __restrict__ Wq, const float* __restrict__ bq,
    const float* __restrict__ Wc, const float* __restrict__ Wout,
    const float* __restrict__ bout,
    ushort_t* __restrict__ Ew, ushort_t* __restrict__ Eu,
    float* __restrict__ Y0, ushort_t* __restrict__ GT)
{
    __shared__ ushort_t As[64 * 72];
    __shared__ ushort_t Ws[64 * 72];
    const int bid = blockIdx.x;

    if (bid < 64) {
        gemm_body<false, false, 4>(As, Ws, inp, Wq, bq, nullptr, Ew,
                                   512, 512, 512, 512, (bid & 7) * 64, (bid >> 3) * 64);
    } else if (bid < 320) {
        int i = bid - 64;
        gemm_body<false, false, 4>(As, Ws, ctx, Wc, nullptr, nullptr, Eu,
                                   512, 512, 512, 512, (i & 31) * 64, (i >> 5) * 64);
    } else if (bid < 576) {
        int i = bid - 320;
        int b = i >> 6, j = i & 63;
        gemm_body<false, false, 2>(As, Ws, Wout, ctx + (size_t)b * 262144, nullptr,
                                   nullptr, GT + (size_t)b * 262144,
                                   512, 1024, 512, 512, (j & 7) * 64, (j >> 3) * 64);
    } else {
        int i = bid - 576;
        gemm_body<false, false, 0>(As, Ws, inp, Wout + 512, bout, nullptr, Y0,
                                   512, 512, 1024, 512, (i & 7) * 64, (i >> 3) * 64);
    }
}

// ---------------------------------------------------------------------------
// K2: Sraw[b,t,s] = V - 2*sum_d v[d]/(1 + Ew[b,t,d]*Eu[b,s,d]),  V = sum v[d]
// Ew/Eu bf16. Wave: 8 t's x 8 s's; lane covers k = {2*lane, 2*lane+1} per
// 128-wide k-chunk (uint = 2 bf16, full 256B/wave coalescing).
// Grid (64, 4, 4) = 1024 blocks; block = 4 waves covering 32 t.
// ---------------------------------------------------------------------------
__global__ __launch_bounds__(256) void align_kernel(
    const ushort_t* __restrict__ Ew, const ushort_t* __restrict__ Eu,
    const float* __restrict__ v, float* __restrict__ out)
{
    const int lane = threadIdx.x & 63, wave = threadIdx.x >> 6;
    const int b = blockIdx.z;
    const int t0 = blockIdx.y * 32 + wave * 8;
    const int s0 = blockIdx.x * 8;

    const unsigned* wp = (const unsigned*)(Ew + (((size_t)(b * 128 + t0)) << 9));
    const unsigned* up = (const unsigned*)(Eu + (((size_t)(b * 512 + s0)) << 9));
    // row stride in uints = 256

    float acc[8][8];
    #pragma unroll
    for (int i = 0; i < 8; ++i)
        #pragma unroll
        for (int j = 0; j < 8; ++j) acc[i][j] = 0.f;
    float vsum = 0.f;

    for (int c0 = 0; c0 < 256; c0 += 64) {          // uint index within row
        float2 vk = *(const float2*)&v[(c0 + lane) * 2];
        vsum += vk.x + vk.y;
        float wlo[8], whi[8];
        #pragma unroll
        for (int tt = 0; tt < 8; ++tt) {
            unsigned wu = wp[tt * 256 + c0 + lane];
            wlo[tt] = bfu_lo(wu);
            whi[tt] = bfu_hi(wu);
        }
        #pragma unroll
        for (int j = 0; j < 8; ++j) {
            unsigned uu = up[j * 256 + c0 + lane];
            float ulo = bfu_lo(uu), uhi = bfu_hi(uu);
            #pragma unroll
            for (int tt = 0; tt < 8; ++tt) {
                float dl = fmaf(wlo[tt], ulo, 1.f);
                float dh = fmaf(whi[tt], uhi, 1.f);
                float rl = __builtin_amdgcn_rcpf(dl);
                float rh = __builtin_amdgcn_rcpf(dh);
                acc[tt][j] = fmaf(vk.x, rl, fmaf(vk.y, rh, acc[tt][j]));
            }
        }
    }

    float V = vsum;
    #pragma unroll
    for (int off = 32; off; off >>= 1) V += __shfl_xor(V, off, 64);

    float res[8];
    #pragma unroll
    for (int tt = 0; tt < 8; ++tt) res[tt] = 0.f;
    #pragma unroll
    for (int j = 0; j < 8; ++j) {
        float a0 = acc[0][j], a1 = acc[1][j], a2 = acc[2][j], a3 = acc[3][j];
        float a4 = acc[4][j], a5 = acc[5][j], a6 = acc[6][j], a7 = acc[7][j];
        #pragma unroll
        for (int off = 32; off; off >>= 1) {
            a0 += __shfl_xor(a0, off, 64);
            a1 += __shfl_xor(a1, off, 64);
            a2 += __shfl_xor(a2, off, 64);
            a3 += __shfl_xor(a3, off, 64);
            a4 += __shfl_xor(a4, off, 64);
            a5 += __shfl_xor(a5, off, 64);
            a6 += __shfl_xor(a6, off, 64);
            a7 += __shfl_xor(a7, off, 64);
        }
        if (lane == j) {
            res[0] = fmaf(-2.f, a0, V);
            res[1] = fmaf(-2.f, a1, V);
            res[2] = fmaf(-2.f, a2, V);
            res[3] = fmaf(-2.f, a3, V);
            res[4] = fmaf(-2.f, a4, V);
            res[5] = fmaf(-2.f, a5, V);
            res[6] = fmaf(-2.f, a6, V);
            res[7] = fmaf(-2.f, a7, V);
        }
    }
    if (lane < 8) {
        size_t o = (((size_t)(b * 128 + t0)) << 9) + s0 + lane;
        #pragma unroll
        for (int tt = 0; tt < 8; ++tt)
            out[o + (size_t)tt * 512] = res[tt];
    }
}

// ---------------------------------------------------------------------------
// K3: softmax over rows of 512. Reads Sraw, writes fp32 alignv + bf16 P.
// ---------------------------------------------------------------------------
__global__ __launch_bounds__(256) void softmax_512(
    const float* __restrict__ Sraw, float* __restrict__ alignv,
    ushort_t* __restrict__ pbf)
{
    const int row = blockIdx.x;
    const float* p = Sraw + ((size_t)row << 9);
    float* a = alignv + ((size_t)row << 9);
    ushort_t* q = pbf + ((size_t)row << 9);
    const int tid = threadIdx.x;
    float x0 = p[tid];
    float x1 = p[tid + 256];

    float m = fmaxf(x0, x1);
    #pragma unroll
    for (int off = 32; off > 0; off >>= 1)
        m = fmaxf(m, __shfl_xor(m, off, 64));
    __shared__ float redm[4];
    __shared__ float reds[4];
    const int wave = tid >> 6;
    if ((tid & 63) == 0) redm[wave] = m;
    __syncthreads();
    m = fmaxf(fmaxf(redm[0], redm[1]), fmaxf(redm[2], redm[3]));

    float e0 = __expf(x0 - m);
    float e1 = __expf(x1 - m);
    float s = e0 + e1;
    #pragma unroll
    for (int off = 32; off > 0; off >>= 1)
        s += __shfl_xor(s, off, 64);
    if ((tid & 63) == 0) reds[wave] = s;
    __syncthreads();
    s = reds[0] + reds[1] + reds[2] + reds[3];
    float r = 1.0f / s;
    float p0 = e0 * r, p1 = e1 * r;
    a[tid] = p0;
    a[tid + 256] = p1;
    q[tid] = f2bf(p0);
    q[tid + 256] = f2bf(p1);
}

// ---------------------------------------------------------------------------
// K4: attn = P_bf @ GT^T + Y0. Per-batch M=128, N=512, K=512. Grid (2,8,4).
// ---------------------------------------------------------------------------
__global__ __launch_bounds__(256) void gemm_att(
    const ushort_t* __restrict__ P, const ushort_t* __restrict__ GT,
    const float* __restrict__ Y0, float* __restrict__ attn)
{
    __shared__ ushort_t As[64 * 72];
    __shared__ ushort_t Ws[64 * 72];
    const int b = blockIdx.z;
    gemm_body<true, true, 3>(As, Ws,
                             P + (size_t)b * 65536, GT + (size_t)b * 262144,
                             nullptr, Y0 + (size_t)b * 65536,
                             attn + (size_t)b * 65536,
                             512, 512, 512, 512, blockIdx.x * 64, blockIdx.y * 64);
}

// ---------------------------------------------------------------------------
extern "C" void kernel_launch(void* const* d_in, const int* in_sizes, int n_in,
                              void* d_out, int out_size, void* d_ws, size_t ws_size,
                              hipStream_t stream)
{
    const float* inp  = (const float*)d_in[0];   // (4,128,512)
    const float* ctx  = (const float*)d_in[1];   // (4,512,512)
    const float* Wq   = (const float*)d_in[2];   // (512,512)
    const float* bq   = (const float*)d_in[3];   // (512)
    const float* Wc   = (const float*)d_in[4];   // (512,512)
    const float* v    = (const float*)d_in[5];   // (512)
    const float* Wout = (const float*)d_in[6];   // (512,1024)
    const float* bout = (const float*)d_in[7];   // (512)

    float* out    = (float*)d_out;
    float* attn   = out;              // 262144 floats
    float* alignv = out + 262144;     // 262144 floats

    float* ws = (float*)d_ws;
    ushort_t* Ew   = (ushort_t*)ws;             // 262144 u16 (= 131072 f)
    ushort_t* Eu   = (ushort_t*)(ws + 131072);  // 1048576 u16 (= 524288 f)
    float* Y0      = ws + 655360;               // 262144 f
    float* Sraw    = ws + 917504;               // 262144 f
    ushort_t* GT   = (ushort_t*)(ws + 1179648); // 1048576 u16 (= 524288 f)
    ushort_t* P_bf = (ushort_t*)(ws + 1703936); // 262144 u16

    fused_front<<<dim3(640), 256, 0, stream>>>(inp, ctx, Wq, bq, Wc, Wout, bout,
                                               Ew, Eu, Y0, GT);
    align_kernel<<<dim3(64, 4, 4), 256, 0, stream>>>(Ew, Eu, v, Sraw);
    softmax_512<<<dim3(512), 256, 0, stream>>>(Sraw, alignv, P_bf);
    gemm_att<<<dim3(2, 8, 4), 256, 0, stream>>>(P_bf, GT, Y0, attn);
}